// Round 14
// baseline (420.610 us; speedup 1.0000x reference)
//
#include <hip/hip_runtime.h>

// GAT layer, N=8192, F_IN=512, F_OUT=256. ALL tensors f32; adj int32.
// out = softmax_row(mask(leaky(s1_i+s2_j))) @ h, h = X@W, s{1,2} = h_f32@a{1,2}.
//
// R23 -> R24:
//  * R23 (128row x quarter-K, B traffic 256 MB) = 409us. B-lever exhausted
//    (-4us for the last halving). attn now rides the 268 MB adj stream
//    (43us pure-HBM floor; per-body 64KB/CU ~= 6400cyc >> 2100cyc compute).
//  * Single lever this round: DROP the nt flag on adj loads. Evidence: R14
//    FETCH_SIZE=151MB < 268MB -> L3 was serving ~45% of adj across bench
//    iterations; nt suppresses cache allocation and may be throttling that.
//    The original nt rationale (protect hTt L2) is obsolete: B-residency
//    perturbations are now worth only ~4us (R23).
//  * Everything else byte-identical to R23. absmax canary 0.0078125.

typedef __attribute__((ext_vector_type(8))) short bf16x8;
typedef __attribute__((ext_vector_type(4))) float fx4;
typedef __attribute__((ext_vector_type(4))) int ix4;
typedef __attribute__((ext_vector_type(2))) unsigned int ux2;

#define NN 8192
#define FIN 512
#define FOUT 256
#define PS 136     // LDS P row stride (shorts); 272B stride -> low-conflict b128
#define AROWS 128  // attn rows per block (x quarter-K split)

__device__ __forceinline__ unsigned short f2bf(float f) {
    unsigned int x = __float_as_uint(f);
    x += 0x7fffu + ((x >> 16) & 1u);
    return (unsigned short)(x >> 16);
}
__device__ __forceinline__ bf16x8 pack8(fx4 a, fx4 b) {
    bf16x8 r;
    r[0] = (short)f2bf(a[0]); r[1] = (short)f2bf(a[1]);
    r[2] = (short)f2bf(a[2]); r[3] = (short)f2bf(a[3]);
    r[4] = (short)f2bf(b[0]); r[5] = (short)f2bf(b[1]);
    r[6] = (short)f2bf(b[2]); r[7] = (short)f2bf(b[3]);
    return r;
}

// ---------- kernel 0: WTt[((k>>5)*256+c)*32 + (k&31)] = bf16(W[k][c]) ----------
__global__ void wt_kernel(const float* __restrict__ W,
                          unsigned short* __restrict__ WTt) {
    const int c = threadIdx.x;
    const int k = blockIdx.x;
    WTt[((size_t)(k >> 5) * 256 + c) * 32 + (k & 31)] = f2bf(W[k * FOUT + c]);
}

// ---------- kernel 1: h-tile (MFMA) + fused s1/s2 ----------
__global__ __launch_bounds__(256) void prep_kernel(
    const float* __restrict__ X,              // 8192x512 f32
    const unsigned short* __restrict__ WTt,   // tiled 256x512 bf16
    const float* __restrict__ A,              // 512 f32 (a1|a2)
    unsigned short* __restrict__ hTt,         // tiled 256x8192 bf16
    float* __restrict__ s1, float* __restrict__ s2)
{
    __shared__ float s1sh[4][16], s2sh[4][16];
    const int tid = threadIdx.x;

    const int w = tid >> 6, l = tid & 63, q = l >> 4, lr = l & 15;
    const int r0 = blockIdx.x * 16;
    const int cbase = w * 64;
    fx4 acc[4] = {};

    for (int kb = 0; kb < FIN; kb += 32) {
        const float* xp = X + (size_t)(r0 + lr) * FIN + kb + q * 8;
        bf16x8 a0 = pack8(*(const fx4*)xp, *(const fx4*)(xp + 4));
#pragma unroll
        for (int tc = 0; tc < 4; ++tc) {
            bf16x8 b = *(const bf16x8*)(WTt + ((size_t)(kb >> 5) * 256 + cbase + tc * 16 + lr) * 32 + q * 8);
            acc[tc] = __builtin_amdgcn_mfma_f32_16x16x32_bf16(a0, b, acc[tc], 0, 0, 0);
        }
    }

    // tiled hTt write
    const int jb = r0 >> 5, jo = (r0 & 31) + q * 4;
#pragma unroll
    for (int tc = 0; tc < 4; ++tc) {
        const int c = cbase + tc * 16 + lr;
        ux2 hp;
        hp.x = (unsigned)f2bf(acc[tc][0]) | ((unsigned)f2bf(acc[tc][1]) << 16);
        hp.y = (unsigned)f2bf(acc[tc][2]) | ((unsigned)f2bf(acc[tc][3]) << 16);
        *(ux2*)(hTt + ((size_t)jb * 256 + c) * 32 + jo) = hp;
    }

    // fused s1/s2 from f32 accumulators
    float p1[4] = {}, p2[4] = {};
#pragma unroll
    for (int tc = 0; tc < 4; ++tc) {
        const int c = cbase + tc * 16 + lr;
        const float a1v = A[c], a2v = A[FOUT + c];
#pragma unroll
        for (int r = 0; r < 4; ++r) {
            p1[r] += acc[tc][r] * a1v;
            p2[r] += acc[tc][r] * a2v;
        }
    }
#pragma unroll
    for (int r = 0; r < 4; ++r) {
#pragma unroll
        for (int off = 1; off < 16; off <<= 1) {
            p1[r] += __shfl_xor(p1[r], off);
            p2[r] += __shfl_xor(p2[r], off);
        }
        if (lr == 0) { s1sh[w][q * 4 + r] = p1[r]; s2sh[w][q * 4 + r] = p2[r]; }
    }
    __syncthreads();
    if (tid < 16) {
        s1[r0 + tid] = s1sh[0][tid] + s1sh[1][tid] + s1sh[2][tid] + s1sh[3][tid];
        s2[r0 + tid] = s2sh[0][tid] + s2sh[1][tid] + s2sh[2][tid] + s2sh[3][tid];
    }
}

// ---------- kernel 2: partial masked-softmax-numerator @ h ----------
// Grid 256 x 512 thr. Block = (rg = bid>>2) rows rg*128..+127, (kq = bid&3)
// K-quarter kq*2048..+2047 (16 bodies of 128 k). Wave w: cols w*32..+31,
// ALL 128 rows via acc[8][2] -> B reused 8x. Per body: phase A = calcP
// (adj prefetched 1 body ahead in regs; s2 batch; B loads issued at top,
// covered by calcP VALU) -> barrier -> phase B = 8x(af ds_read + 8 MFMA)
// -> barrier. Writes partial num (f32) + den per K-quarter.
__global__ __launch_bounds__(512, 2) void attn_kernel(
    const int* __restrict__ adj,             // 8192 x 8192 i32
    const unsigned short* __restrict__ hTt,  // tiled 256 x 8192 bf16
    const float* __restrict__ s1,
    const float* __restrict__ s2,
    float* __restrict__ num,                 // 4 x 8192 x 256 f32 partial
    float* __restrict__ den)                 // 4 x 8192 f32 partial
{
    __shared__ unsigned short P[AROWS * PS];   // 34.8 KB single buffer

    const int tid = threadIdx.x;
    const int rg = blockIdx.x >> 2;
    const int kq = blockIdx.x & 3;             // K-quarter (XCD-aligned)
    const int r0 = rg * AROWS;
    const int kb0 = kq * 16;                   // first 128k-tile of this quarter

    // P-generation role: thread -> (row, 8-k slice per 32-k group)
    const int prow = tid >> 2;                 // 0..127
    const int pq = tid & 3;                    // k = j8*32 + pq*8
    const float s1v = s1[r0 + prow];
    const int* arow = adj + (size_t)(r0 + prow) * NN + kq * 2048 + pq * 8;
    float denp = 0.f;

    // MFMA role: wave w -> cols w*32..+31, rows 0..127 (8 row-frags)
    const int w = tid >> 6, l = tid & 63, q = l >> 4, lr = l & 15;
    const int cbase = w * 32;
    fx4 acc[8][2] = {};

    ix4 av[8];                                 // adj for current body (4 j8 x 2)
    bf16x8 B[4][2];                            // single-buffered B

    auto loadA = [&](int it) {                 // adj for body it -> av
        const int* ap = arow + it * 128;
#pragma unroll
        for (int j8 = 0; j8 < 4; ++j8) {
            av[2 * j8]     = *(const ix4*)(ap + j8 * 32);       // cached: let L3
            av[2 * j8 + 1] = *(const ix4*)(ap + j8 * 32 + 4);   // retain adj
        }
    };
    auto loadB = [&](int it) {
        const int kt = kb0 + it;
#pragma unroll
        for (int ks = 0; ks < 4; ++ks)
#pragma unroll
            for (int tc = 0; tc < 2; ++tc)
                B[ks][tc] = *(const bf16x8*)(hTt + ((size_t)(kt * 4 + ks) * 256 + cbase + tc * 16 + lr) * 32 + q * 8);
    };
    auto phaseA = [&](int it) {                // consumes av, writes P
        fx4 s2v[8];
        const float* sp = s2 + (kb0 + it) * 128 + pq * 8;
#pragma unroll
        for (int j8 = 0; j8 < 4; ++j8) {
            s2v[2 * j8]     = *(const fx4*)(sp + j8 * 32);
            s2v[2 * j8 + 1] = *(const fx4*)(sp + j8 * 32 + 4);
        }
#pragma unroll
        for (int j8 = 0; j8 < 4; ++j8) {
            bf16x8 pv;
#pragma unroll
            for (int j = 0; j < 8; ++j) {
                const int aj = (j < 4) ? av[2 * j8][j] : av[2 * j8 + 1][j - 4];
                const float s2j = (j < 4) ? s2v[2 * j8][j] : s2v[2 * j8 + 1][j - 4];
                float t = s1v + s2j;
                float e = fmaxf(t, 0.2f * t);  // leaky_relu, alpha=0.2
                e = fminf(e, 30.f);            // overflow guard (inactive)
                const float p = (aj != 0) ? __expf(e) : 0.f;
                denp += p;
                pv[j] = (short)f2bf(p);
            }
            *(bf16x8*)(&P[prow * PS + j8 * 32 + pq * 8]) = pv;   // 16B store
        }
    };
    auto ldsBarrier = [&]() {
        asm volatile("s_waitcnt lgkmcnt(0)" ::: "memory");
        __builtin_amdgcn_s_barrier();
    };

    const int ITERS = 16;         // bodies (128 k each) in this K-quarter

    loadA(0);
    for (int it = 0; it < ITERS; ++it) {
        loadB(it);                             // covered by phase A VALU
        phaseA(it);                            // consumes av, writes P
        if (it + 1 < ITERS) loadA(it + 1);     // refill av (1 body of flight)
        ldsBarrier();                          // P visible; B/adj in flight
#pragma unroll
        for (int rg8 = 0; rg8 < 8; ++rg8) {    // 8 row-frags reuse B
            bf16x8 af[4];
#pragma unroll
            for (int ks = 0; ks < 4; ++ks)
                af[ks] = *(const bf16x8*)(&P[(rg8 * 16 + lr) * PS + ks * 32 + q * 8]);
            __builtin_amdgcn_s_setprio(1);
#pragma unroll
            for (int ks = 0; ks < 4; ++ks)
#pragma unroll
                for (int tc = 0; tc < 2; ++tc)
                    acc[rg8][tc] = __builtin_amdgcn_mfma_f32_16x16x32_bf16(af[ks], B[ks][tc], acc[rg8][tc], 0, 0, 0);
            __builtin_amdgcn_s_setprio(0);
        }
        ldsBarrier();                          // P consumed -> safe to overwrite
    }

    // partial den: reduce over the 4 lanes sharing a row
    float v = denp;
    v += __shfl_xor(v, 1);
    v += __shfl_xor(v, 2);
    if (pq == 0) den[(size_t)kq * NN + r0 + prow] = v;

    // partial num: raw f32 accumulators
    float* nb = num + (size_t)kq * NN * FOUT;
#pragma unroll
    for (int rg8 = 0; rg8 < 8; ++rg8)
#pragma unroll
        for (int r = 0; r < 4; ++r) {
            const int row = rg8 * 16 + q * 4 + r;
#pragma unroll
            for (int tc = 0; tc < 2; ++tc)
                nb[(size_t)(r0 + row) * FOUT + cbase + tc * 16 + lr] = acc[rg8][tc][r];
        }
}

// ---------- kernel 3: combine K-quarter partials, divide by total den ----------
// 1024 blocks x 512 thr = 524288 threads; one fx4 (4 cols of one row) each.
__global__ __launch_bounds__(512) void combine_kernel(
    const float* __restrict__ num, const float* __restrict__ den,
    float* __restrict__ out)
{
    const size_t NF = (size_t)NN * FOUT;
    const int idx = blockIdx.x * 512 + threadIdx.x;   // fx4 index, 524288 total
    const int r = idx >> 6;                           // 64 fx4 per 256-col row
    const fx4 a = *(const fx4*)(num + (size_t)idx * 4);
    const fx4 b = *(const fx4*)(num + NF + (size_t)idx * 4);
    const fx4 c = *(const fx4*)(num + 2 * NF + (size_t)idx * 4);
    const fx4 d = *(const fx4*)(num + 3 * NF + (size_t)idx * 4);
    const float dt = den[r] + den[NN + r] + den[2 * NN + r] + den[3 * NN + r];
    const float dinv = 1.0f / fmaxf(dt, 1e-30f);
    fx4 o;
#pragma unroll
    for (int j = 0; j < 4; ++j) o[j] = (a[j] + b[j] + c[j] + d[j]) * dinv;
    *(fx4*)(out + (size_t)idx * 4) = o;
}

extern "C" void kernel_launch(void* const* d_in, const int* in_sizes, int n_in,
                              void* d_out, int out_size, void* d_ws, size_t ws_size,
                              hipStream_t stream) {
    const float *X = nullptr, *W = nullptr, *A = nullptr;
    const int* adj = nullptr;
    for (int i = 0; i < n_in; ++i) {
        switch (in_sizes[i]) {
            case NN * FIN:   X = (const float*)d_in[i]; break;
            case FIN * FOUT: W = (const float*)d_in[i]; break;
            case 2 * FOUT:   A = (const float*)d_in[i]; break;
            case NN * NN:    adj = (const int*)d_in[i]; break;
        }
    }
    if (!X) X = (const float*)d_in[0];
    if (!W) W = (const float*)d_in[1];
    if (!A) A = (const float*)d_in[2];
    if (!adj) adj = (const int*)d_in[3];
    float* out = (float*)d_out;

    // ws layout (~42 MB of the 1 GiB ws):
    char* ws = (char*)d_ws;
    float* s1 = (float*)ws;                                 // 32 KB
    float* s2 = (float*)(ws + 32768);                       // 32 KB
    unsigned short* WTt = (unsigned short*)(ws + 98304);    // 256 KB
    unsigned short* hTt = (unsigned short*)(ws + 360448);   // 4 MB
    float* num = (float*)(ws + 8388608);                    // 4 x 8 MB partials
    float* den = (float*)(ws + 41943040);                   // 4 x 32 KB partials

    wt_kernel<<<512, 256, 0, stream>>>(W, WTt);
    prep_kernel<<<512, 256, 0, stream>>>(X, WTt, A, hTt, s1, s2);
    attn_kernel<<<(NN / AROWS) * 4, 512, 0, stream>>>(adj, hTt, s1, s2, num, den);
    combine_kernel<<<1024, 512, 0, stream>>>(num, den, out);
}